// Round 5
// baseline (5675.225 us; speedup 1.0000x reference)
//
#include <hip/hip_runtime.h>
#include <hip/hip_bf16.h>
#include <stdint.h>

#define T_SEQ 512
#define HID   512
#define BATCH 128
#define G_B   8
#define G_N   32
#define BB    (BATCH / G_B)     // 16 batch rows per WG
#define HC    (HID / G_N)       // 16 h-cols per WG
#define NROW  (3 * HC)          // 48 W rows per matrix chunk
#define HFIN  (BATCH * HID)
#define WSTR  512               // LDS row stride in shorts; XOR-swizzled

using f32x4  = __attribute__((ext_vector_type(4))) float;
using short8 = __attribute__((ext_vector_type(8))) short;
using bfs4   = __attribute__((ext_vector_type(4))) short;
using u32x4  = __attribute__((ext_vector_type(4))) unsigned int;

__device__ __forceinline__ short8 pack8(float a0, float a1, float a2, float a3,
                                        float a4, float a5, float a6, float a7) {
    union { uint32_t u[4]; short8 s; } r;
    asm("v_cvt_pk_bf16_f32 %0, %1, %2" : "=v"(r.u[0]) : "v"(a0), "v"(a1));
    asm("v_cvt_pk_bf16_f32 %0, %1, %2" : "=v"(r.u[1]) : "v"(a2), "v"(a3));
    asm("v_cvt_pk_bf16_f32 %0, %1, %2" : "=v"(r.u[2]) : "v"(a4), "v"(a5));
    asm("v_cvt_pk_bf16_f32 %0, %1, %2" : "=v"(r.u[3]) : "v"(a6), "v"(a7));
    return r.s;
}

__device__ __forceinline__ uint16_t f2bf(float f) {  // RNE
    uint32_t u = __builtin_bit_cast(uint32_t, f);
    return (uint16_t)((u + 0x7fffu + ((u >> 16) & 1u)) >> 16);
}

// LDS index with XOR swizzle (16B-block swap within 128B span per row)
__device__ __forceinline__ int lws(int row, int ko) {
    return row * WSTR + (ko ^ ((row & 7) << 3));
}

__global__ void __launch_bounds__(64, 1) gru_scan(
    const float* __restrict__ hidden,   // [B][H]
    const float* __restrict__ ins,      // [B][T][H]
    const int*   __restrict__ resets,   // [B][T]
    const float* __restrict__ W_ih,     // [3H][H]
    const float* __restrict__ W_hh,     // [3H][H]
    const float* __restrict__ b_ih,     // [3H]
    const float* __restrict__ b_hh,     // [3H]
    float* __restrict__ out,            // [B*H] h_final, then [B][T][H] ys
    uint32_t* __restrict__ xb)          // [2][B][H] (tag<<16|bf16) ping-pong
{
    __shared__ __align__(16) short ldsW[2][NROW * WSTR];   // 96 KB

    const int wg   = blockIdx.x;
    const int bb   = wg & 7;            // batch block (XCD-local by %8 dispatch)
    const int nn   = wg >> 3;           // h-col chunk 0..31
    const int lane = threadIdx.x;       // single wave
    const int l15  = lane & 15;
    const int lg   = lane >> 4;         // 0..3

    // ---- one-time: W chunks -> LDS (bf16, swizzled) ----
    for (int idx = lane; idx < NROW * (HID / 4); idx += 64) {
        const int row = idx >> 7;              // 0..47
        const int k4  = (idx & 127) << 2;
        const int g   = row >> 4;              // gate 0..2 (r,z,n)
        const int i   = row & 15;
        const int grow = g * HID + nn * HC + i;
        f32x4 wi = *(const f32x4*)&W_ih[(size_t)grow * HID + k4];
        f32x4 wh = *(const f32x4*)&W_hh[(size_t)grow * HID + k4];
        bfs4 si = { (short)f2bf(wi[0]), (short)f2bf(wi[1]), (short)f2bf(wi[2]), (short)f2bf(wi[3]) };
        bfs4 sh = { (short)f2bf(wh[0]), (short)f2bf(wh[1]), (short)f2bf(wh[2]), (short)f2bf(wh[3]) };
        *(bfs4*)&ldsW[0][lws(row, k4)] = si;
        *(bfs4*)&ldsW[1][lws(row, k4)] = sh;
    }
    __syncthreads();

    const int arow  = bb * BB + l15;            // A-operand batch row
    const int drow0 = bb * BB + lg * 4;         // D-side batch row base
    const int dcol  = nn * HC + l15;            // D-side h col

    const float bir = b_ih[dcol], biz = b_ih[HID + dcol], bin_ = b_ih[2 * HID + dcol];
    const float bhr = b_hh[dcol], bhz = b_hh[HID + dcol], bhn  = b_hh[2 * HID + dcol];

    float hprev[4];                             // own h(t-1) at (drow0+j, dcol)
    #pragma unroll
    for (int j = 0; j < 4; ++j)
        hprev[j] = hidden[(size_t)(drow0 + j) * HID + dcol];

    float* const ys = out + HFIN;

    for (int t = 0; t < T_SEQ; ++t) {
        // ---------- input GEMM gi (independent of h(t-1)) ----------
        f32x4 aIr = {0,0,0,0}, aIz = {0,0,0,0}, aIn = {0,0,0,0};
        const float* xrow = ins + ((size_t)arow * T_SEQ + t) * HID + lg * 8;
        #pragma unroll
        for (int kt = 0; kt < 16; ++kt) {
            f32x4 x0 = *(const f32x4*)(xrow + kt * 32);
            f32x4 x1 = *(const f32x4*)(xrow + kt * 32 + 4);
            short8 af = pack8(x0[0], x0[1], x0[2], x0[3], x1[0], x1[1], x1[2], x1[3]);
            const int ko = kt * 32 + lg * 8;
            aIr = __builtin_amdgcn_mfma_f32_16x16x32_bf16(af, *(const short8*)&ldsW[0][lws(l15, ko)], aIr, 0, 0, 0);
            aIz = __builtin_amdgcn_mfma_f32_16x16x32_bf16(af, *(const short8*)&ldsW[0][lws(16 + l15, ko)], aIz, 0, 0, 0);
            aIn = __builtin_amdgcn_mfma_f32_16x16x32_bf16(af, *(const short8*)&ldsW[0][lws(32 + l15, ko)], aIn, 0, 0, 0);
        }

        const int rstA = resets[(size_t)arow * T_SEQ + t];

        // ---------- acquire h(t-1): self-validating tagged loads ----------
        short8 ah[16];
        if (t == 0) {
            const float* hrow = hidden + (size_t)arow * HID + lg * 8;
            const float am = rstA ? 0.f : 1.f;
            #pragma unroll
            for (int kt = 0; kt < 16; ++kt) {
                f32x4 h0 = *(const f32x4*)(hrow + kt * 32);
                f32x4 h1 = *(const f32x4*)(hrow + kt * 32 + 4);
                ah[kt] = pack8(am * h0[0], am * h0[1], am * h0[2], am * h0[3],
                               am * h1[0], am * h1[1], am * h1[2], am * h1[3]);
            }
        } else {
            const uint32_t wtag = (uint32_t)t << 16;   // tag of h(t-1) is (t-1)+1
            const uint32_t* hb = xb + (size_t)((t - 1) & 1) * HFIN
                                    + (size_t)arow * HID + lg * 8;
            u32x4 d[32];
#define PL(K, O0, O1) \
    asm volatile("global_load_dwordx4 %0, %2, off offset:" O0 " sc0 sc1\n\t" \
                 "global_load_dwordx4 %1, %2, off offset:" O1 " sc0 sc1" \
                 : "=v"(d[2*K]), "=v"(d[2*K+1]) : "v"(hb) : "memory")
            for (;;) {
                PL(0,  "0",    "16");   PL(1,  "128",  "144");
                PL(2,  "256",  "272");  PL(3,  "384",  "400");
                PL(4,  "512",  "528");  PL(5,  "640",  "656");
                PL(6,  "768",  "784");  PL(7,  "896",  "912");
                PL(8,  "1024", "1040"); PL(9,  "1152", "1168");
                PL(10, "1280", "1296"); PL(11, "1408", "1424");
                PL(12, "1536", "1552"); PL(13, "1664", "1680");
                PL(14, "1792", "1808"); PL(15, "1920", "1936");
                asm volatile("s_waitcnt vmcnt(0)" ::: "memory");
                uint32_t bad = 0;
                #pragma unroll
                for (int q = 0; q < 32; ++q) {
                    bad |= (d[q][0] ^ wtag) & 0xffff0000u;
                    bad |= (d[q][1] ^ wtag) & 0xffff0000u;
                    bad |= (d[q][2] ^ wtag) & 0xffff0000u;
                    bad |= (d[q][3] ^ wtag) & 0xffff0000u;
                }
                if (!__any((int)(bad != 0))) break;
                __builtin_amdgcn_s_sleep(1);
            }
#undef PL
            __builtin_amdgcn_sched_barrier(0);
            // strip tags: pack 8 dword-lows -> short8 (v_perm)
            #pragma unroll
            for (int kt = 0; kt < 16; ++kt) {
                union { uint32_t w[4]; short8 s; } r;
                r.w[0] = __builtin_amdgcn_perm(d[2*kt][1],   d[2*kt][0],   0x05040100u);
                r.w[1] = __builtin_amdgcn_perm(d[2*kt][3],   d[2*kt][2],   0x05040100u);
                r.w[2] = __builtin_amdgcn_perm(d[2*kt+1][1], d[2*kt+1][0], 0x05040100u);
                r.w[3] = __builtin_amdgcn_perm(d[2*kt+1][3], d[2*kt+1][2], 0x05040100u);
                ah[kt] = r.s;
            }
            if (rstA) {
                const short8 z8 = {0,0,0,0,0,0,0,0};
                #pragma unroll
                for (int kt = 0; kt < 16; ++kt) ah[kt] = z8;
            }
        }

        // ---------- hidden GEMM gh ----------
        f32x4 aHr = {0,0,0,0}, aHz = {0,0,0,0}, aHn = {0,0,0,0};
        #pragma unroll
        for (int kt = 0; kt < 16; ++kt) {
            const int ko = kt * 32 + lg * 8;
            aHr = __builtin_amdgcn_mfma_f32_16x16x32_bf16(ah[kt], *(const short8*)&ldsW[1][lws(l15, ko)], aHr, 0, 0, 0);
            aHz = __builtin_amdgcn_mfma_f32_16x16x32_bf16(ah[kt], *(const short8*)&ldsW[1][lws(16 + l15, ko)], aHz, 0, 0, 0);
            aHn = __builtin_amdgcn_mfma_f32_16x16x32_bf16(ah[kt], *(const short8*)&ldsW[1][lws(32 + l15, ko)], aHn, 0, 0, 0);
        }

        // ---------- gates + stores (D: col=lane&15, row=(lane>>4)*4+j) ----------
        #pragma unroll
        for (int j = 0; j < 4; ++j) {
            const int r_ = drow0 + j;
            const int rstD = resets[(size_t)r_ * T_SEQ + t];
            const float hp = rstD ? 0.f : hprev[j];
            const float gr = aIr[j] + bir + aHr[j] + bhr;
            const float rg = 1.f / (1.f + __expf(-gr));
            const float gz = aIz[j] + biz + aHz[j] + bhz;
            const float zg = 1.f / (1.f + __expf(-gz));
            float gn = aIn[j] + bin_ + rg * (aHn[j] + bhn);
            gn = fminf(fmaxf(gn, -15.f), 15.f);
            const float e2 = __expf(2.f * gn);
            const float ng = (e2 - 1.f) / (e2 + 1.f);
            const float hn = (1.f - zg) * ng + zg * hp;
            hprev[j] = hn;
            ys[((size_t)r_ * T_SEQ + t) * HID + dcol] = hn;
            if (t == T_SEQ - 1) {
                out[(size_t)r_ * HID + dcol] = hn;
            } else {
                uint32_t v = ((uint32_t)(t + 1) << 16) | f2bf(hn);
                uint32_t* p = xb + (size_t)(t & 1) * HFIN + (size_t)r_ * HID + dcol;
                asm volatile("global_store_dword %0, %1, off sc0 sc1"
                             :: "v"(p), "v"(v) : "memory");
            }
        }
        // no publish drain needed: next step's poll does vmcnt(0) before any
        // same-address slot reuse, and consumers poll tags directly.
    }
}

extern "C" void kernel_launch(void* const* d_in, const int* in_sizes, int n_in,
                              void* d_out, int out_size, void* d_ws, size_t ws_size,
                              hipStream_t stream) {
    const float* hidden = (const float*)d_in[0];
    const float* ins    = (const float*)d_in[1];
    const int*   resets = (const int*)d_in[2];
    const float* W_ih   = (const float*)d_in[3];
    const float* W_hh   = (const float*)d_in[4];
    const float* b_ih   = (const float*)d_in[5];
    const float* b_hh   = (const float*)d_in[6];
    float* out = (float*)d_out;
    uint32_t* xb = (uint32_t*)d_ws;

    hipMemsetAsync(xb, 0, (size_t)2 * HFIN * 4, stream);   // tags=0 invalid
    gru_scan<<<dim3(G_B * G_N), dim3(64), 0, stream>>>(
        hidden, ins, resets, W_ih, W_hh, b_ih, b_hh, out, xb);
}

// Round 6
// 2618.987 us; speedup vs baseline: 2.1670x; 2.1670x over previous
//
#include <hip/hip_runtime.h>
#include <hip/hip_bf16.h>
#include <stdint.h>

#define T_SEQ 512
#define HID   512
#define BATCH 128
#define G_B   8
#define G_N   32
#define BB    (BATCH / G_B)     // 16 batch rows per WG
#define HC    (HID / G_N)       // 16 h-cols per WG
#define NROW  (3 * HC)          // 48 W rows per matrix chunk
#define HFIN  (BATCH * HID)
#define WSTR  512               // LDS row stride in shorts; XOR-swizzled

using f32x4  = __attribute__((ext_vector_type(4))) float;
using short8 = __attribute__((ext_vector_type(8))) short;
using bfs4   = __attribute__((ext_vector_type(4))) short;

__device__ __forceinline__ short8 pack8(float a0, float a1, float a2, float a3,
                                        float a4, float a5, float a6, float a7) {
    union { uint32_t u[4]; short8 s; } r;
    asm("v_cvt_pk_bf16_f32 %0, %1, %2" : "=v"(r.u[0]) : "v"(a0), "v"(a1));
    asm("v_cvt_pk_bf16_f32 %0, %1, %2" : "=v"(r.u[1]) : "v"(a2), "v"(a3));
    asm("v_cvt_pk_bf16_f32 %0, %1, %2" : "=v"(r.u[2]) : "v"(a4), "v"(a5));
    asm("v_cvt_pk_bf16_f32 %0, %1, %2" : "=v"(r.u[3]) : "v"(a6), "v"(a7));
    return r.s;
}

__device__ __forceinline__ uint16_t f2bf(float f) {  // RNE
    uint32_t u = __builtin_bit_cast(uint32_t, f);
    return (uint16_t)((u + 0x7fffu + ((u >> 16) & 1u)) >> 16);
}

__device__ __forceinline__ int lws(int row, int ko) {   // LDS XOR swizzle
    return row * WSTR + (ko ^ ((row & 7) << 3));
}

__global__ void __launch_bounds__(64, 1) gru_scan(
    const float* __restrict__ hidden,   // [B][H]
    const float* __restrict__ ins,      // [B][T][H]
    const int*   __restrict__ resets,   // [B][T]
    const float* __restrict__ W_ih,     // [3H][H]
    const float* __restrict__ W_hh,     // [3H][H]
    const float* __restrict__ b_ih,     // [3H]
    const float* __restrict__ b_hh,     // [3H]
    float* __restrict__ out,            // [B*H] h_final, then [B][T][H] ys
    uint32_t* __restrict__ flags,       // [G_B][32] done-flags (monotonic step tags)
    unsigned short* __restrict__ xbs)   // [2][B][H] bf16 h exchange (ping-pong)
{
    __shared__ __align__(16) short ldsW[2][NROW * WSTR];   // 96 KB

    const int wg   = blockIdx.x;
    const int bb   = wg & 7;            // batch block (XCD-local by %8 dispatch)
    const int nn   = wg >> 3;           // h-col chunk 0..31
    const int lane = threadIdx.x;       // single wave
    const int l15  = lane & 15;
    const int lg   = lane >> 4;         // 0..3

    // ---- one-time: W chunks -> LDS (bf16, swizzled) ----
    for (int idx = lane; idx < NROW * (HID / 4); idx += 64) {
        const int row = idx >> 7;              // 0..47
        const int k4  = (idx & 127) << 2;
        const int g   = row >> 4;              // gate 0..2 (r,z,n)
        const int i   = row & 15;
        const int grow = g * HID + nn * HC + i;
        f32x4 wi = *(const f32x4*)&W_ih[(size_t)grow * HID + k4];
        f32x4 wh = *(const f32x4*)&W_hh[(size_t)grow * HID + k4];
        bfs4 si = { (short)f2bf(wi[0]), (short)f2bf(wi[1]), (short)f2bf(wi[2]), (short)f2bf(wi[3]) };
        bfs4 sh = { (short)f2bf(wh[0]), (short)f2bf(wh[1]), (short)f2bf(wh[2]), (short)f2bf(wh[3]) };
        *(bfs4*)&ldsW[0][lws(row, k4)] = si;
        *(bfs4*)&ldsW[1][lws(row, k4)] = sh;
    }
    __syncthreads();

    const int arow  = bb * BB + l15;            // A-operand batch row
    const int drow0 = bb * BB + lg * 4;         // D-side batch row base
    const int dcol  = nn * HC + l15;            // D-side h col

    const float bir = b_ih[dcol], biz = b_ih[HID + dcol], bin_ = b_ih[2 * HID + dcol];
    const float bhr = b_hh[dcol], bhz = b_hh[HID + dcol], bhn  = b_hh[2 * HID + dcol];

    float hprev[4];                             // own h(t-1) at (drow0+j, dcol)
    #pragma unroll
    for (int j = 0; j < 4; ++j)
        hprev[j] = hidden[(size_t)(drow0 + j) * HID + dcol];

    float* const ys = out + HFIN;
    const uint32_t* fp = flags + bb * 32 + (lane & 31);   // poll addr (2x dup)
    uint32_t* const fme = flags + bb * 32 + nn;           // my flag

    const float* const xbase = ins + (size_t)arow * T_SEQ * HID + lg * 8;

    // ---- prologue: x(0) into registers ----
    f32x4 xr[32];
    #pragma unroll
    for (int i = 0; i < 16; ++i) {
        xr[2 * i]     = *(const f32x4*)(xbase + i * 32);
        xr[2 * i + 1] = *(const f32x4*)(xbase + i * 32 + 4);
    }

    for (int t = 0; t < T_SEQ; ++t) {
        // ---------- convert x(t) -> bf16 fragments ----------
        short8 af[16];
        #pragma unroll
        for (int kt = 0; kt < 16; ++kt)
            af[kt] = pack8(xr[2*kt][0], xr[2*kt][1], xr[2*kt][2], xr[2*kt][3],
                           xr[2*kt+1][0], xr[2*kt+1][1], xr[2*kt+1][2], xr[2*kt+1][3]);

        // ---------- prefetch x(t+1) (lands during poll/gh) ----------
        {
            const int tn = (t + 1 < T_SEQ) ? t + 1 : T_SEQ - 1;
            const float* xn = xbase + (size_t)tn * HID;
            #pragma unroll
            for (int i = 0; i < 16; ++i) {
                xr[2 * i]     = *(const f32x4*)(xn + i * 32);
                xr[2 * i + 1] = *(const f32x4*)(xn + i * 32 + 4);
            }
        }

        // ---------- input GEMM gi ----------
        f32x4 aIr = {0,0,0,0}, aIz = {0,0,0,0}, aIn = {0,0,0,0};
        #pragma unroll
        for (int kt = 0; kt < 16; ++kt) {
            const int ko = kt * 32 + lg * 8;
            aIr = __builtin_amdgcn_mfma_f32_16x16x32_bf16(af[kt], *(const short8*)&ldsW[0][lws(l15, ko)], aIr, 0, 0, 0);
            aIz = __builtin_amdgcn_mfma_f32_16x16x32_bf16(af[kt], *(const short8*)&ldsW[0][lws(16 + l15, ko)], aIz, 0, 0, 0);
            aIn = __builtin_amdgcn_mfma_f32_16x16x32_bf16(af[kt], *(const short8*)&ldsW[0][lws(32 + l15, ko)], aIn, 0, 0, 0);
        }

        const int rstA = resets[(size_t)arow * T_SEQ + t];

        // ---------- acquire h(t-1) ----------
        short8 ah[16];
        if (t == 0) {
            const float* hrow = hidden + (size_t)arow * HID + lg * 8;
            const float am = rstA ? 0.f : 1.f;
            #pragma unroll
            for (int kt = 0; kt < 16; ++kt) {
                f32x4 h0 = *(const f32x4*)(hrow + kt * 32);
                f32x4 h1 = *(const f32x4*)(hrow + kt * 32 + 4);
                ah[kt] = pack8(am * h0[0], am * h0[1], am * h0[2], am * h0[3],
                               am * h1[0], am * h1[1], am * h1[2], am * h1[3]);
            }
        } else {
            // poll 32 done-flags (128B/wave/iter, LLC-coherent)
            uint32_t f;
            do {
                asm volatile("global_load_dword %0, %1, off sc0 sc1\n\t"
                             "s_waitcnt vmcnt(0)"
                             : "=v"(f) : "v"(fp) : "memory");
            } while (!__all((int)(f >= (uint32_t)t)));
            __builtin_amdgcn_sched_barrier(0);

            const unsigned short* hb = xbs + (size_t)((t - 1) & 1) * HFIN
                                           + (size_t)arow * HID + lg * 8;
#define LOADH(K, OFFS) \
    asm volatile("global_load_dwordx4 %0, %1, off offset:" OFFS " sc0 sc1" \
                 : "=v"(ah[K]) : "v"(hb) : "memory")
            LOADH(0, "0");    LOADH(1, "64");   LOADH(2, "128");  LOADH(3, "192");
            LOADH(4, "256");  LOADH(5, "320");  LOADH(6, "384");  LOADH(7, "448");
            LOADH(8, "512");  LOADH(9, "576");  LOADH(10, "640"); LOADH(11, "704");
            LOADH(12, "768"); LOADH(13, "832"); LOADH(14, "896"); LOADH(15, "960");
#undef LOADH
            asm volatile("s_waitcnt vmcnt(0)" ::: "memory");
            __builtin_amdgcn_sched_barrier(0);
            if (rstA) {
                const short8 z8 = {0,0,0,0,0,0,0,0};
                #pragma unroll
                for (int kt = 0; kt < 16; ++kt) ah[kt] = z8;
            }
        }

        // ---------- hidden GEMM gh ----------
        f32x4 aHr = {0,0,0,0}, aHz = {0,0,0,0}, aHn = {0,0,0,0};
        #pragma unroll
        for (int kt = 0; kt < 16; ++kt) {
            const int ko = kt * 32 + lg * 8;
            aHr = __builtin_amdgcn_mfma_f32_16x16x32_bf16(ah[kt], *(const short8*)&ldsW[1][lws(l15, ko)], aHr, 0, 0, 0);
            aHz = __builtin_amdgcn_mfma_f32_16x16x32_bf16(ah[kt], *(const short8*)&ldsW[1][lws(16 + l15, ko)], aHz, 0, 0, 0);
            aHn = __builtin_amdgcn_mfma_f32_16x16x32_bf16(ah[kt], *(const short8*)&ldsW[1][lws(32 + l15, ko)], aHn, 0, 0, 0);
        }

        // ---------- gates (D: col=lane&15, row=(lane>>4)*4+j) ----------
        float hnv[4];
        #pragma unroll
        for (int j = 0; j < 4; ++j) {
            const int r_ = drow0 + j;
            const int rstD = resets[(size_t)r_ * T_SEQ + t];
            const float hp = rstD ? 0.f : hprev[j];
            const float gr = aIr[j] + bir + aHr[j] + bhr;
            const float rg = 1.f / (1.f + __expf(-gr));
            const float gz = aIz[j] + biz + aHz[j] + bhz;
            const float zg = 1.f / (1.f + __expf(-gz));
            float gn = aIn[j] + bin_ + rg * (aHn[j] + bhn);
            gn = fminf(fmaxf(gn, -15.f), 15.f);
            const float e2 = __expf(2.f * gn);
            const float ng = (e2 - 1.f) / (e2 + 1.f);
            const float hn = (1.f - zg) * ng + zg * hp;
            hprev[j] = hn;
            hnv[j] = hn;
        }

        // ---------- publish h(t) FIRST (bf16 data -> drain -> flag) ----------
        if (t < T_SEQ - 1) {
            #pragma unroll
            for (int j = 0; j < 4; ++j) {
                uint32_t v = f2bf(hnv[j]);
                unsigned short* p = xbs + (size_t)(t & 1) * HFIN
                                        + (size_t)(drow0 + j) * HID + dcol;
                asm volatile("global_store_short %0, %1, off sc0 sc1"
                             :: "v"(p), "v"(v) : "memory");
            }
            asm volatile("s_waitcnt vmcnt(0)" ::: "memory");
            if (lane == 0) {
                uint32_t tag = (uint32_t)(t + 1);
                asm volatile("global_store_dword %0, %1, off sc0 sc1"
                             :: "v"(fme), "v"(tag) : "memory");
            }
        }

        // ---------- ys (and h_final) stores, off the critical path ----------
        #pragma unroll
        for (int j = 0; j < 4; ++j) {
            const int r_ = drow0 + j;
            ys[((size_t)r_ * T_SEQ + t) * HID + dcol] = hnv[j];
            if (t == T_SEQ - 1) out[(size_t)r_ * HID + dcol] = hnv[j];
        }
    }
}

extern "C" void kernel_launch(void* const* d_in, const int* in_sizes, int n_in,
                              void* d_out, int out_size, void* d_ws, size_t ws_size,
                              hipStream_t stream) {
    const float* hidden = (const float*)d_in[0];
    const float* ins    = (const float*)d_in[1];
    const int*   resets = (const int*)d_in[2];
    const float* W_ih   = (const float*)d_in[3];
    const float* W_hh   = (const float*)d_in[4];
    const float* b_ih   = (const float*)d_in[5];
    const float* b_hh   = (const float*)d_in[6];
    float* out = (float*)d_out;
    uint32_t* flags = (uint32_t*)d_ws;
    unsigned short* xbs = (unsigned short*)((char*)d_ws + 1024);

    hipMemsetAsync(flags, 0, 1024, stream);     // step tags start at 1
    gru_scan<<<dim3(G_B * G_N), dim3(64), 0, stream>>>(
        hidden, ins, resets, W_ih, W_hh, b_ih, b_hh, out, flags, xbs);
}

// Round 7
// 2217.099 us; speedup vs baseline: 2.5598x; 1.1813x over previous
//
#include <hip/hip_runtime.h>
#include <hip/hip_bf16.h>
#include <stdint.h>

#define T_SEQ 512
#define HID   512
#define BATCH 128
#define G_B   8
#define G_N   32
#define BB    (BATCH / G_B)     // 16 batch rows per WG
#define HC    (HID / G_N)       // 16 h-cols per WG
#define NROW  (3 * HC)          // 48 W rows per matrix chunk
#define HFIN  (BATCH * HID)
#define WSTR  512               // W LDS row stride in shorts; XOR-swizzled
#define XSTR  520               // x LDS row stride in floats (8-pad -> 4-way max)

using f32x4  = __attribute__((ext_vector_type(4))) float;
using short8 = __attribute__((ext_vector_type(8))) short;
using bfs4   = __attribute__((ext_vector_type(4))) short;

typedef const __attribute__((address_space(1))) void* gas_t;
typedef __attribute__((address_space(3))) void* las_t;

__device__ __forceinline__ short8 pack8(float a0, float a1, float a2, float a3,
                                        float a4, float a5, float a6, float a7) {
    union { uint32_t u[4]; short8 s; } r;
    asm("v_cvt_pk_bf16_f32 %0, %1, %2" : "=v"(r.u[0]) : "v"(a0), "v"(a1));
    asm("v_cvt_pk_bf16_f32 %0, %1, %2" : "=v"(r.u[1]) : "v"(a2), "v"(a3));
    asm("v_cvt_pk_bf16_f32 %0, %1, %2" : "=v"(r.u[2]) : "v"(a4), "v"(a5));
    asm("v_cvt_pk_bf16_f32 %0, %1, %2" : "=v"(r.u[3]) : "v"(a6), "v"(a7));
    return r.s;
}

__device__ __forceinline__ uint16_t f2bf(float f) {  // RNE
    uint32_t u = __builtin_bit_cast(uint32_t, f);
    return (uint16_t)((u + 0x7fffu + ((u >> 16) & 1u)) >> 16);
}

__device__ __forceinline__ int lws(int row, int ko) {   // W LDS XOR swizzle
    return row * WSTR + (ko ^ ((row & 7) << 3));
}

__global__ void __launch_bounds__(64, 1) gru_scan(
    const float* __restrict__ hidden,   // [B][H]
    const float* __restrict__ ins,      // [B][T][H]
    const int*   __restrict__ resets,   // [B][T]
    const float* __restrict__ W_ih,     // [3H][H]
    const float* __restrict__ W_hh,     // [3H][H]
    const float* __restrict__ b_ih,     // [3H]
    const float* __restrict__ b_hh,     // [3H]
    float* __restrict__ out,            // [B*H] h_final, then [B][T][H] ys
    uint32_t* __restrict__ flags,       // [G_B][32] done-flags (step tags)
    unsigned short* __restrict__ xbs)   // [2][B][H] bf16 h exchange (ping-pong)
{
    __shared__ __align__(16) short ldsW[2][NROW * WSTR];   // 96 KB
    __shared__ __align__(16) float ldsX[BB * XSTR];        // 32.5 KB

    const int wg   = blockIdx.x;
    const int bb   = wg & 7;            // batch block (XCD-local by %8 dispatch)
    const int nn   = wg >> 3;           // h-col chunk 0..31
    const int lane = threadIdx.x;       // single wave
    const int l15  = lane & 15;
    const int lg   = lane >> 4;         // 0..3

    // async stage of x(t) into ldsX: 32 x 16B per lane-set, linear dest
#define STAGE_X(T_) do {                                                      \
        _Pragma("unroll")                                                     \
        for (int i_ = 0; i_ < 32; ++i_) {                                     \
            const int r_ = i_ >> 1, hf_ = i_ & 1;                             \
            const float* src_ = ins + ((size_t)(bb * BB + r_) * T_SEQ + (T_)) \
                                   * HID + hf_ * 256 + lane * 4;              \
            float* dst_ = (float*)&ldsX[r_ * XSTR + hf_ * 256];               \
            __builtin_amdgcn_global_load_lds((gas_t)src_, (las_t)dst_,        \
                                             16, 0, 0);                       \
        }                                                                     \
    } while (0)

    // ---- prologue: kick off x(0) DMA, then stage W chunks -> LDS ----
    STAGE_X(0);
    for (int idx = lane; idx < NROW * (HID / 4); idx += 64) {
        const int row = idx >> 7;              // 0..47
        const int k4  = (idx & 127) << 2;
        const int g   = row >> 4;              // gate 0..2 (r,z,n)
        const int i   = row & 15;
        const int grow = g * HID + nn * HC + i;
        f32x4 wi = *(const f32x4*)&W_ih[(size_t)grow * HID + k4];
        f32x4 wh = *(const f32x4*)&W_hh[(size_t)grow * HID + k4];
        bfs4 si = { (short)f2bf(wi[0]), (short)f2bf(wi[1]), (short)f2bf(wi[2]), (short)f2bf(wi[3]) };
        bfs4 sh = { (short)f2bf(wh[0]), (short)f2bf(wh[1]), (short)f2bf(wh[2]), (short)f2bf(wh[3]) };
        *(bfs4*)&ldsW[0][lws(row, k4)] = si;
        *(bfs4*)&ldsW[1][lws(row, k4)] = sh;
    }
    asm volatile("s_waitcnt vmcnt(0) lgkmcnt(0)" ::: "memory");
    __builtin_amdgcn_sched_barrier(0);

    const int arow  = bb * BB + l15;            // A-operand batch row
    const int drow0 = bb * BB + lg * 4;         // D-side batch row base
    const int dcol  = nn * HC + l15;            // D-side h col

    const float bir = b_ih[dcol], biz = b_ih[HID + dcol], bin_ = b_ih[2 * HID + dcol];
    const float bhr = b_hh[dcol], bhz = b_hh[HID + dcol], bhn  = b_hh[2 * HID + dcol];

    float hprev[4];                             // own h(t-1) at (drow0+j, dcol)
    #pragma unroll
    for (int j = 0; j < 4; ++j)
        hprev[j] = hidden[(size_t)(drow0 + j) * HID + dcol];

    float* const ys = out + HFIN;
    const uint32_t* fp = flags + bb * 32 + (lane & 31);   // poll addr
    uint32_t* const fme = flags + bb * 32 + nn;           // my flag

    for (int t = 0; t < T_SEQ; ++t) {
        // ---------- convert x(t) (LDS) -> bf16 fragments ----------
        short8 af[16];
        const float* xr = &ldsX[l15 * XSTR + lg * 8];
        #pragma unroll
        for (int kt = 0; kt < 16; ++kt) {
            f32x4 x0 = *(const f32x4*)(xr + kt * 32);
            f32x4 x1 = *(const f32x4*)(xr + kt * 32 + 4);
            af[kt] = pack8(x0[0], x0[1], x0[2], x0[3], x1[0], x1[1], x1[2], x1[3]);
        }
        asm volatile("s_waitcnt lgkmcnt(0)" ::: "memory");   // x reads retired
        __builtin_amdgcn_sched_barrier(0);

        // ---------- kick off x(t+1) DMA (drains inside the poll) ----------
        if (t + 1 < T_SEQ) STAGE_X(t + 1);

        // ---------- input GEMM gi ----------
        f32x4 aIr = {0,0,0,0}, aIz = {0,0,0,0}, aIn = {0,0,0,0};
        #pragma unroll
        for (int kt = 0; kt < 16; ++kt) {
            const int ko = kt * 32 + lg * 8;
            aIr = __builtin_amdgcn_mfma_f32_16x16x32_bf16(af[kt], *(const short8*)&ldsW[0][lws(l15, ko)], aIr, 0, 0, 0);
            aIz = __builtin_amdgcn_mfma_f32_16x16x32_bf16(af[kt], *(const short8*)&ldsW[0][lws(16 + l15, ko)], aIz, 0, 0, 0);
            aIn = __builtin_amdgcn_mfma_f32_16x16x32_bf16(af[kt], *(const short8*)&ldsW[0][lws(32 + l15, ko)], aIn, 0, 0, 0);
        }

        const int rstA = resets[(size_t)arow * T_SEQ + t];

        // ---------- acquire h(t-1) ----------
        short8 ah[16];
        if (t == 0) {
            const float* hrow = hidden + (size_t)arow * HID + lg * 8;
            const float am = rstA ? 0.f : 1.f;
            #pragma unroll
            for (int kt = 0; kt < 16; ++kt) {
                f32x4 h0 = *(const f32x4*)(hrow + kt * 32);
                f32x4 h1 = *(const f32x4*)(hrow + kt * 32 + 4);
                ah[kt] = pack8(am * h0[0], am * h0[1], am * h0[2], am * h0[3],
                               am * h1[0], am * h1[1], am * h1[2], am * h1[3]);
            }
        } else {
            // poll 32 done-flags; vmcnt(0) also drains x-DMA + ys acks (hidden)
            uint32_t f;
            do {
                asm volatile("global_load_dword %0, %1, off sc0 sc1\n\t"
                             "s_waitcnt vmcnt(0)"
                             : "=v"(f) : "v"(fp) : "memory");
            } while (!__all((int)(f >= (uint32_t)t)));
            __builtin_amdgcn_sched_barrier(0);

            const unsigned short* hb = xbs + (size_t)((t - 1) & 1) * HFIN
                                           + (size_t)arow * HID + lg * 8;
#define LOADH(K, OFFS) \
    asm volatile("global_load_dwordx4 %0, %1, off offset:" OFFS " sc0 sc1" \
                 : "=v"(ah[K]) : "v"(hb) : "memory")
            LOADH(0, "0");    LOADH(1, "64");   LOADH(2, "128");  LOADH(3, "192");
            LOADH(4, "256");  LOADH(5, "320");  LOADH(6, "384");  LOADH(7, "448");
            LOADH(8, "512");  LOADH(9, "576");  LOADH(10, "640"); LOADH(11, "704");
            LOADH(12, "768"); LOADH(13, "832"); LOADH(14, "896"); LOADH(15, "960");
#undef LOADH
            asm volatile("s_waitcnt vmcnt(0)" ::: "memory");
            __builtin_amdgcn_sched_barrier(0);
            if (rstA) {
                const short8 z8 = {0,0,0,0,0,0,0,0};
                #pragma unroll
                for (int kt = 0; kt < 16; ++kt) ah[kt] = z8;
            }
        }

        // ---------- hidden GEMM gh ----------
        f32x4 aHr = {0,0,0,0}, aHz = {0,0,0,0}, aHn = {0,0,0,0};
        #pragma unroll
        for (int kt = 0; kt < 16; ++kt) {
            const int ko = kt * 32 + lg * 8;
            aHr = __builtin_amdgcn_mfma_f32_16x16x32_bf16(ah[kt], *(const short8*)&ldsW[1][lws(l15, ko)], aHr, 0, 0, 0);
            aHz = __builtin_amdgcn_mfma_f32_16x16x32_bf16(ah[kt], *(const short8*)&ldsW[1][lws(16 + l15, ko)], aHz, 0, 0, 0);
            aHn = __builtin_amdgcn_mfma_f32_16x16x32_bf16(ah[kt], *(const short8*)&ldsW[1][lws(32 + l15, ko)], aHn, 0, 0, 0);
        }

        // ---------- gates (D: col=lane&15, row=(lane>>4)*4+j) ----------
        float hnv[4];
        #pragma unroll
        for (int j = 0; j < 4; ++j) {
            const int r_ = drow0 + j;
            const int rstD = resets[(size_t)r_ * T_SEQ + t];
            const float hp = rstD ? 0.f : hprev[j];
            const float gr = aIr[j] + bir + aHr[j] + bhr;
            const float rg = 1.f / (1.f + __expf(-gr));
            const float gz = aIz[j] + biz + aHz[j] + bhz;
            const float zg = 1.f / (1.f + __expf(-gz));
            float gn = aIn[j] + bin_ + rg * (aHn[j] + bhn);
            gn = fminf(fmaxf(gn, -15.f), 15.f);
            const float e2 = __expf(2.f * gn);
            const float ng = (e2 - 1.f) / (e2 + 1.f);
            const float hn = (1.f - zg) * ng + zg * hp;
            hprev[j] = hn;
            hnv[j] = hn;
        }

        // ---------- publish h(t): bf16 data -> drain (own acks only) -> flag ----------
        if (t < T_SEQ - 1) {
            #pragma unroll
            for (int j = 0; j < 4; ++j) {
                uint32_t v = f2bf(hnv[j]);
                unsigned short* p = xbs + (size_t)(t & 1) * HFIN
                                        + (size_t)(drow0 + j) * HID + dcol;
                asm volatile("global_store_short %0, %1, off sc0 sc1"
                             :: "v"(p), "v"(v) : "memory");
            }
            asm volatile("s_waitcnt vmcnt(0)" ::: "memory");
            if (lane == 0) {
                uint32_t tag = (uint32_t)(t + 1);
                asm volatile("global_store_dword %0, %1, off sc0 sc1"
                             :: "v"(fme), "v"(tag) : "memory");
            }
        }

        // ---------- ys (and h_final) stores, acks drained in next poll ----------
        #pragma unroll
        for (int j = 0; j < 4; ++j) {
            const int r_ = drow0 + j;
            ys[((size_t)r_ * T_SEQ + t) * HID + dcol] = hnv[j];
            if (t == T_SEQ - 1) out[(size_t)r_ * HID + dcol] = hnv[j];
        }
    }
#undef STAGE_X
}

extern "C" void kernel_launch(void* const* d_in, const int* in_sizes, int n_in,
                              void* d_out, int out_size, void* d_ws, size_t ws_size,
                              hipStream_t stream) {
    const float* hidden = (const float*)d_in[0];
    const float* ins    = (const float*)d_in[1];
    const int*   resets = (const int*)d_in[2];
    const float* W_ih   = (const float*)d_in[3];
    const float* W_hh   = (const float*)d_in[4];
    const float* b_ih   = (const float*)d_in[5];
    const float* b_hh   = (const float*)d_in[6];
    float* out = (float*)d_out;
    uint32_t* flags = (uint32_t*)d_ws;
    unsigned short* xbs = (unsigned short*)((char*)d_ws + 1024);

    hipMemsetAsync(flags, 0, 1024, stream);     // step tags start at 1
    gru_scan<<<dim3(G_B * G_N), dim3(64), 0, stream>>>(
        hidden, ins, resets, W_ih, W_hh, b_ih, b_hh, out, flags, xbs);
}

// Round 8
// 1719.725 us; speedup vs baseline: 3.3001x; 1.2892x over previous
//
#include <hip/hip_runtime.h>
#include <hip/hip_bf16.h>
#include <stdint.h>

#define T_SEQ 512
#define HID   512
#define BATCH 128
#define G_B   8
#define G_N   32
#define BB    (BATCH / G_B)     // 16 batch rows per WG
#define HC    (HID / G_N)       // 16 h-cols per WG
#define NROW  (3 * HC)          // 48 W rows per matrix chunk
#define HFIN  (BATCH * HID)
#define WSTR  512               // W LDS row stride in shorts; XOR-swizzled
#define XSTR  520               // x LDS row stride in floats
#define GSTR  20                // gi handoff stride in floats (16B-aligned)

using f32x4  = __attribute__((ext_vector_type(4))) float;
using short8 = __attribute__((ext_vector_type(8))) short;
using bfs4   = __attribute__((ext_vector_type(4))) short;

typedef const __attribute__((address_space(1))) void* gas_t;
typedef __attribute__((address_space(3))) void* las_t;

__device__ __forceinline__ short8 pack8(float a0, float a1, float a2, float a3,
                                        float a4, float a5, float a6, float a7) {
    union { uint32_t u[4]; short8 s; } r;
    asm("v_cvt_pk_bf16_f32 %0, %1, %2" : "=v"(r.u[0]) : "v"(a0), "v"(a1));
    asm("v_cvt_pk_bf16_f32 %0, %1, %2" : "=v"(r.u[1]) : "v"(a2), "v"(a3));
    asm("v_cvt_pk_bf16_f32 %0, %1, %2" : "=v"(r.u[2]) : "v"(a4), "v"(a5));
    asm("v_cvt_pk_bf16_f32 %0, %1, %2" : "=v"(r.u[3]) : "v"(a6), "v"(a7));
    return r.s;
}

__device__ __forceinline__ uint16_t f2bf(float f) {  // RNE
    uint32_t u = __builtin_bit_cast(uint32_t, f);
    return (uint16_t)((u + 0x7fffu + ((u >> 16) & 1u)) >> 16);
}

__device__ __forceinline__ int lws(int row, int ko) {   // W LDS XOR swizzle
    return row * WSTR + (ko ^ ((row & 7) << 3));
}

__global__ void __launch_bounds__(128, 1) gru_scan(
    const float* __restrict__ hidden,   // [B][H]
    const float* __restrict__ ins,      // [B][T][H]
    const int*   __restrict__ resets,   // [B][T]
    const float* __restrict__ W_ih,     // [3H][H]
    const float* __restrict__ W_hh,     // [3H][H]
    const float* __restrict__ b_ih,     // [3H]
    const float* __restrict__ b_hh,     // [3H]
    float* __restrict__ out,            // [B*H] h_final, then [B][T][H] ys
    uint32_t* __restrict__ flags,       // [G_B][32] done-flags (step tags)
    unsigned short* __restrict__ xbs)   // [2][B][H] bf16 h exchange (ping-pong)
{
    __shared__ __align__(16) short ldsW[2][NROW * WSTR];   // 96 KB
    __shared__ __align__(16) float ldsX[BB * XSTR];        // 32.5 KB
    __shared__ __align__(16) float giB[64 * GSTR];         // 5 KB gi handoff
    __shared__ __align__(16) float hnvB[64 * 4];           // 1 KB hnv handoff

    const int wg   = blockIdx.x;
    const int bb   = wg & 7;            // batch block (XCD-local by %8 dispatch)
    const int nn   = wg >> 3;           // h-col chunk 0..31
    const int tid  = threadIdx.x;
    const int lane = tid & 63;
    const int wv   = tid >> 6;          // 0 = sync wave, 1 = gi wave
    const int l15  = lane & 15;
    const int lg   = lane >> 4;

#define STAGE_X(T_) do {                                                      \
        _Pragma("unroll")                                                     \
        for (int i_ = 0; i_ < 32; ++i_) {                                     \
            const int r_ = i_ >> 1, hf_ = i_ & 1;                             \
            const float* src_ = ins + ((size_t)(bb * BB + r_) * T_SEQ + (T_)) \
                                   * HID + hf_ * 256 + lane * 4;              \
            float* dst_ = (float*)&ldsX[r_ * XSTR + hf_ * 256];               \
            __builtin_amdgcn_global_load_lds((gas_t)src_, (las_t)dst_,        \
                                             16, 0, 0);                       \
        }                                                                     \
    } while (0)

    if (wv) STAGE_X(0);                 // gi wave kicks x(0) DMA

    // ---- cooperative W staging (both waves) ----
    for (int idx = tid; idx < NROW * (HID / 4); idx += 128) {
        const int row = idx >> 7;
        const int k4  = (idx & 127) << 2;
        const int g   = row >> 4;
        const int i   = row & 15;
        const int grow = g * HID + nn * HC + i;
        f32x4 wi = *(const f32x4*)&W_ih[(size_t)grow * HID + k4];
        f32x4 wh = *(const f32x4*)&W_hh[(size_t)grow * HID + k4];
        bfs4 si = { (short)f2bf(wi[0]), (short)f2bf(wi[1]), (short)f2bf(wi[2]), (short)f2bf(wi[3]) };
        bfs4 sh = { (short)f2bf(wh[0]), (short)f2bf(wh[1]), (short)f2bf(wh[2]), (short)f2bf(wh[3]) };
        *(bfs4*)&ldsW[0][lws(row, k4)] = si;
        *(bfs4*)&ldsW[1][lws(row, k4)] = sh;
    }
    __syncthreads();    // prologue-only full drain (also completes x(0) DMA)

    const int arow  = bb * BB + l15;
    const int drow0 = bb * BB + lg * 4;
    const int dcol  = nn * HC + l15;
    float* const ys = out + HFIN;

    if (wv) {
        // ================= gi wave =================
        for (int t = 0; t < T_SEQ; ++t) {
            // x(t) DMA completion (issued >1 sync-section ago)
            asm volatile("s_waitcnt vmcnt(0)" ::: "memory");
            __builtin_amdgcn_sched_barrier(0);

            short8 af[16];
            const float* xr = &ldsX[l15 * XSTR + lg * 8];
            #pragma unroll
            for (int kt = 0; kt < 16; ++kt) {
                f32x4 x0 = *(const f32x4*)(xr + kt * 32);
                f32x4 x1 = *(const f32x4*)(xr + kt * 32 + 4);
                af[kt] = pack8(x0[0], x0[1], x0[2], x0[3], x1[0], x1[1], x1[2], x1[3]);
            }

            f32x4 aIr = {0,0,0,0}, aIz = {0,0,0,0}, aIn = {0,0,0,0};
            #pragma unroll
            for (int kt = 0; kt < 16; ++kt) {
                const int ko = kt * 32 + lg * 8;
                aIr = __builtin_amdgcn_mfma_f32_16x16x32_bf16(af[kt], *(const short8*)&ldsW[0][lws(l15, ko)], aIr, 0, 0, 0);
                aIz = __builtin_amdgcn_mfma_f32_16x16x32_bf16(af[kt], *(const short8*)&ldsW[0][lws(16 + l15, ko)], aIz, 0, 0, 0);
                aIn = __builtin_amdgcn_mfma_f32_16x16x32_bf16(af[kt], *(const short8*)&ldsW[0][lws(32 + l15, ko)], aIn, 0, 0, 0);
            }
            *(f32x4*)&giB[lane * GSTR + 0] = aIr;
            *(f32x4*)&giB[lane * GSTR + 4] = aIz;
            *(f32x4*)&giB[lane * GSTR + 8] = aIn;
            asm volatile("s_waitcnt lgkmcnt(0)" ::: "memory");   // giB + ldsX reads retired
            __builtin_amdgcn_s_barrier();                        // A: gi(t) ready
            if (t + 1 < T_SEQ) STAGE_X(t + 1);                   // flies through publish
            __builtin_amdgcn_s_barrier();                        // B: hnv(t) ready

            f32x4 hn = *(const f32x4*)&hnvB[lane * 4];
            #pragma unroll
            for (int j = 0; j < 4; ++j) {
                const int r_ = drow0 + j;
                ys[((size_t)r_ * T_SEQ + t) * HID + dcol] = hn[j];
                if (t == T_SEQ - 1) out[(size_t)r_ * HID + dcol] = hn[j];
            }
        }
    } else {
        // ================= sync wave =================
        const float bir = b_ih[dcol], biz = b_ih[HID + dcol], bin_ = b_ih[2 * HID + dcol];
        const float bhr = b_hh[dcol], bhz = b_hh[HID + dcol], bhn  = b_hh[2 * HID + dcol];

        float hprev[4];
        #pragma unroll
        for (int j = 0; j < 4; ++j)
            hprev[j] = hidden[(size_t)(drow0 + j) * HID + dcol];

        const uint32_t* fp = flags + bb * 32 + (lane & 31);
        uint32_t* const fme = flags + bb * 32 + nn;

        for (int t = 0; t < T_SEQ; ++t) {
            short8 ah[16];
            int rstA, rstD[4];
            rstA = resets[(size_t)arow * T_SEQ + t];
            #pragma unroll
            for (int j = 0; j < 4; ++j)
                rstD[j] = resets[(size_t)(drow0 + j) * T_SEQ + t];

            if (t == 0) {
                const float* hrow = hidden + (size_t)arow * HID + lg * 8;
                const float am = rstA ? 0.f : 1.f;
                #pragma unroll
                for (int kt = 0; kt < 16; ++kt) {
                    f32x4 h0 = *(const f32x4*)(hrow + kt * 32);
                    f32x4 h1 = *(const f32x4*)(hrow + kt * 32 + 4);
                    ah[kt] = pack8(am * h0[0], am * h0[1], am * h0[2], am * h0[3],
                                   am * h1[0], am * h1[1], am * h1[2], am * h1[3]);
                }
            } else {
                uint32_t f;
                do {
                    asm volatile("global_load_dword %0, %1, off sc0 sc1\n\t"
                                 "s_waitcnt vmcnt(0)"
                                 : "=v"(f) : "v"(fp) : "memory");
                } while (!__all((int)(f >= (uint32_t)t)));
                __builtin_amdgcn_sched_barrier(0);

                const unsigned short* hb = xbs + (size_t)((t - 1) & 1) * HFIN
                                               + (size_t)arow * HID + lg * 8;
#define LOADH(K, OFFS) \
    asm volatile("global_load_dwordx4 %0, %1, off offset:" OFFS " sc0 sc1" \
                 : "=v"(ah[K]) : "v"(hb) : "memory")
                LOADH(0, "0");    LOADH(1, "64");   LOADH(2, "128");  LOADH(3, "192");
                LOADH(4, "256");  LOADH(5, "320");  LOADH(6, "384");  LOADH(7, "448");
                LOADH(8, "512");  LOADH(9, "576");  LOADH(10, "640"); LOADH(11, "704");
                LOADH(12, "768"); LOADH(13, "832"); LOADH(14, "896"); LOADH(15, "960");
#undef LOADH
                asm volatile("s_waitcnt vmcnt(0)" ::: "memory");
                __builtin_amdgcn_sched_barrier(0);
                if (rstA) {
                    const short8 z8 = {0,0,0,0,0,0,0,0};
                    #pragma unroll
                    for (int kt = 0; kt < 16; ++kt) ah[kt] = z8;
                }
            }

            __builtin_amdgcn_s_barrier();                        // A: gi(t) ready

            f32x4 aIr = *(const f32x4*)&giB[lane * GSTR + 0];
            f32x4 aIz = *(const f32x4*)&giB[lane * GSTR + 4];
            f32x4 aIn = *(const f32x4*)&giB[lane * GSTR + 8];

            f32x4 aHr = {0,0,0,0}, aHz = {0,0,0,0}, aHn = {0,0,0,0};
            #pragma unroll
            for (int kt = 0; kt < 16; ++kt) {
                const int ko = kt * 32 + lg * 8;
                aHr = __builtin_amdgcn_mfma_f32_16x16x32_bf16(ah[kt], *(const short8*)&ldsW[1][lws(l15, ko)], aHr, 0, 0, 0);
                aHz = __builtin_amdgcn_mfma_f32_16x16x32_bf16(ah[kt], *(const short8*)&ldsW[1][lws(16 + l15, ko)], aHz, 0, 0, 0);
                aHn = __builtin_amdgcn_mfma_f32_16x16x32_bf16(ah[kt], *(const short8*)&ldsW[1][lws(32 + l15, ko)], aHn, 0, 0, 0);
            }

            f32x4 hv;
            #pragma unroll
            for (int j = 0; j < 4; ++j) {
                const float hp = rstD[j] ? 0.f : hprev[j];
                const float gr = aIr[j] + bir + aHr[j] + bhr;
                const float rg = 1.f / (1.f + __expf(-gr));
                const float gz = aIz[j] + biz + aHz[j] + bhz;
                const float zg = 1.f / (1.f + __expf(-gz));
                float gn = aIn[j] + bin_ + rg * (aHn[j] + bhn);
                gn = fminf(fmaxf(gn, -15.f), 15.f);
                const float e2 = __expf(2.f * gn);
                const float ng = (e2 - 1.f) / (e2 + 1.f);
                const float hn = (1.f - zg) * ng + zg * hp;
                hprev[j] = hn;
                hv[j] = hn;
            }
            *(f32x4*)&hnvB[lane * 4] = hv;

            if (t < T_SEQ - 1) {
                #pragma unroll
                for (int j = 0; j < 4; ++j) {
                    uint32_t v = f2bf(hv[j]);
                    unsigned short* p = xbs + (size_t)(t & 1) * HFIN
                                            + (size_t)(drow0 + j) * HID + dcol;
                    asm volatile("global_store_short %0, %1, off sc0 sc1"
                                 :: "v"(p), "v"(v) : "memory");
                }
                asm volatile("s_waitcnt vmcnt(0)" ::: "memory");
                if (lane == 0) {
                    uint32_t tag = (uint32_t)(t + 1);
                    asm volatile("global_store_dword %0, %1, off sc0 sc1"
                                 :: "v"(fme), "v"(tag) : "memory");
                }
            }
            asm volatile("s_waitcnt lgkmcnt(0)" ::: "memory");   // hnvB visible
            __builtin_amdgcn_s_barrier();                        // B: hnv(t) ready
        }
    }
#undef STAGE_X
}

extern "C" void kernel_launch(void* const* d_in, const int* in_sizes, int n_in,
                              void* d_out, int out_size, void* d_ws, size_t ws_size,
                              hipStream_t stream) {
    const float* hidden = (const float*)d_in[0];
    const float* ins    = (const float*)d_in[1];
    const int*   resets = (const int*)d_in[2];
    const float* W_ih   = (const float*)d_in[3];
    const float* W_hh   = (const float*)d_in[4];
    const float* b_ih   = (const float*)d_in[5];
    const float* b_hh   = (const float*)d_in[6];
    float* out = (float*)d_out;
    uint32_t* flags = (uint32_t*)d_ws;
    unsigned short* xbs = (unsigned short*)((char*)d_ws + 1024);

    hipMemsetAsync(flags, 0, 1024, stream);     // step tags start at 1
    gru_scan<<<dim3(G_B * G_N), dim3(128), 0, stream>>>(
        hidden, ins, resets, W_ih, W_hh, b_ih, b_hh, out, flags, xbs);
}